// Round 14
// baseline (176.902 us; speedup 1.0000x reference)
//
#include <hip/hip_runtime.h>
#include <hip/hip_bf16.h>
#include <cstddef>

#define N_NODES 50000
#define N_EDGES_RAW 800000
#define E_TOT (N_EDGES_RAW + N_NODES) /* 850000 */
#define DIM 128
#define NEG_SLOPE 0.2f

#define NBUCK 196            /* ceil(50000/256) buckets of 256 nodes */
#define CHUNK 4096           /* edges per block in bucket passes */
#define NBLK_E ((E_TOT + CHUNK - 1) / CHUNK) /* 208 */
#define CONV_BLKS 3125       /* 6.4M f32 -> bf16, 2048 elems/block */
#define GB 782               /* gemm blocks: ceil(3125 tiles / 4 waves) */

typedef __attribute__((ext_vector_type(8))) short bf16x8;
typedef __attribute__((ext_vector_type(4))) float f32x4;

// round-to-nearest-even f32 -> bf16 bits
__device__ __forceinline__ ushort f2bf(float f) {
  unsigned u = __float_as_uint(f);
  return (ushort)((u + 0x7FFFu + ((u >> 16) & 1u)) >> 16);
}
__device__ __forceinline__ float bf2f_lo(uint u) {
  return __uint_as_float(u << 16);
}
__device__ __forceinline__ float bf2f_hi(uint u) {
  return __uint_as_float(u & 0xFFFF0000u);
}

// ---------- edge fetch robust to int32 vs int64 storage of edge_index ----------
__device__ __forceinline__ void get_edge(const int* __restrict__ ei, int is64,
                                         int e, int& s, int& d) {
  if (e >= N_EDGES_RAW) { s = e - N_EDGES_RAW; d = s; return; }
  if (is64) {
    s = ei[2 * (size_t)e];
    d = ei[2 * ((size_t)N_EDGES_RAW + (size_t)e)];
  } else {
    s = ei[e];
    d = ei[N_EDGES_RAW + e];
  }
}

__device__ __forceinline__ int detect_inline(const int* __restrict__ ei,
                                             int* sflag) {
  const int t = threadIdx.x;
  if (t < 64) {
    int hi = ei[2 * t + 1];
    unsigned long long b = __ballot(hi != 0);
    if (t == 0) *sflag = (b == 0ULL) ? 1 : 0;
  }
  __syncthreads();
  return *sflag;
}

// ---------- WtX1[144][128] bf16 prep (W1^T + score columns) ----------
__device__ __forceinline__ void prep_one(const float* __restrict__ w,
                                         const float* __restrict__ atts,
                                         const float* __restrict__ attd,
                                         ushort* __restrict__ wtx,
                                         int H, int idx) {
  const int c = idx >> 7, k = idx & 127;
  const int C = 128 / H;
  float v;
  if (c < 128) {
    v = w[k * 128 + c];
  } else if (c < 128 + H) {
    const int hd = c - 128;
    float s = 0.f;
    for (int j = 0; j < C; ++j) s += w[k * 128 + hd * C + j] * atts[hd * C + j];
    v = s;
  } else if (c < 128 + 2 * H) {
    const int hd = c - 128 - H;
    float s = 0.f;
    for (int j = 0; j < C; ++j) s += w[k * 128 + hd * C + j] * attd[hd * C + j];
    v = s;
  } else {
    v = 0.f;
  }
  wtx[idx] = f2bf(v);
}

// ---------- mega: wtx1 | wtx2 (W2^T) | w_as2/w_ad2 | x->bf16 | hist+pairs ----
__global__ __launch_bounds__(256) void mega_setup(
    const int* __restrict__ ei, int* __restrict__ hist_mat,
    unsigned* __restrict__ pairs,
    const float* __restrict__ W1, const float* __restrict__ as1,
    const float* __restrict__ ad1,
    const float* __restrict__ W2, const float* __restrict__ as2,
    const float* __restrict__ ad2,
    const float* __restrict__ x, ushort* __restrict__ x_bf,
    ushort* __restrict__ wtx1, ushort* __restrict__ wtx2,
    float* __restrict__ w_as2, float* __restrict__ w_ad2) {
  const int b = blockIdx.x, t = threadIdx.x;
  if (b < 72) {
    prep_one(W1, as1, ad1, wtx1, 4, b * 256 + t);
  } else if (b < 136) {
    const int idx = (b - 72) * 256 + t;  // 0..16383
    const int c = idx >> 7, k = idx & 127;
    wtx2[idx] = f2bf(W2[k * 128 + c]);   // wtx2[c][k] = W2[k][c]
  } else if (b == 136) {
    if (t < 128) {
      float s2 = 0.f, d2 = 0.f;
      for (int c = 0; c < 128; ++c) {
        float w = W2[t * 128 + c];
        s2 += w * as2[c];
        d2 += w * ad2[c];
      }
      w_as2[t] = s2;
      w_ad2[t] = d2;
    }
  } else if (b < 137 + CONV_BLKS) {
    const int base = (b - 137) * 2048 + t * 8;
    float4 v0 = *(const float4*)(x + base);
    float4 v1 = *(const float4*)(x + base + 4);
    ushort u[8];
    u[0] = f2bf(v0.x); u[1] = f2bf(v0.y); u[2] = f2bf(v0.z); u[3] = f2bf(v0.w);
    u[4] = f2bf(v1.x); u[5] = f2bf(v1.y); u[6] = f2bf(v1.z); u[7] = f2bf(v1.w);
    *(uint4*)(x_bf + base) = *(const uint4*)u;
  } else {
    __shared__ int hist[NBUCK];
    __shared__ int sflag;
    const int cb = b - 137 - CONV_BLKS;
    if (t < NBUCK) hist[t] = 0;
    const int is64 = detect_inline(ei, &sflag);  // has __syncthreads
    __syncthreads();
    const int e0 = cb * CHUNK;
#pragma unroll
    for (int i = 0; i < CHUNK / 256; ++i) {
      int e = e0 + i * 256 + t;
      if (e < E_TOT) {
        int s, d;
        get_edge(ei, is64, e, s, d);
        pairs[e] = (unsigned)s | ((unsigned)d << 16);
        atomicAdd(&hist[d >> 8], 1);
      }
    }
    __syncthreads();
    if (t < NBUCK) hist_mat[cb * NBUCK + t] = hist[t];
  }
}

// ---------- scatter with self-computed deterministic bases (no global atomics) --
__global__ __launch_bounds__(256) void bucket_scatter(
    const unsigned* __restrict__ pairs, const int* __restrict__ hist_mat,
    unsigned* __restrict__ tmp, int* __restrict__ bstart_g) {
  __shared__ int wtot[4];
  __shared__ int sbase[NBUCK];
  __shared__ int shist[NBUCK];
  const int b = blockIdx.x, t = threadIdx.x, lane = t & 63, wid = t >> 6;
  int tot = 0, pre = 0;
  if (t < NBUCK) {
    for (int bb = 0; bb < NBLK_E; ++bb) {
      int v = hist_mat[bb * NBUCK + t];
      pre += (bb < b) ? v : 0;
      tot += v;
    }
    shist[t] = 0;
  }
  int sc = tot;
#pragma unroll
  for (int m = 1; m < 64; m <<= 1) {
    int o = __shfl_up(sc, m, 64);
    if (lane >= m) sc += o;
  }
  if (lane == 63) wtot[wid] = sc;
  __syncthreads();
  int off = 0;
  for (int w = 0; w < wid; ++w) off += wtot[w];
  const int excl = off + sc - tot;
  if (t < NBUCK) sbase[t] = excl + pre;
  if (b == 0) {
    if (t < NBUCK) bstart_g[t] = excl;
    if (t == 255) bstart_g[NBUCK] = off + sc;
  }
  __syncthreads();
  const int e0 = b * CHUNK;
  unsigned pr_[CHUNK / 256];
  int rk[CHUNK / 256];
#pragma unroll
  for (int i = 0; i < CHUNK / 256; ++i) {
    int e = e0 + i * 256 + t;
    if (e < E_TOT) {
      unsigned pr = pairs[e];
      pr_[i] = pr;
      rk[i] = atomicAdd(&shist[pr >> 24], 1);
    }
  }
#pragma unroll
  for (int i = 0; i < CHUNK / 256; ++i) {
    int e = e0 + i * 256 + t;
    if (e < E_TOT) tmp[sbase[pr_[i] >> 24] + rk[i]] = pr_[i];
  }
}

// ---------- per-bucket counting sort body (emits PACKED (s|d<<16) csr) --------
__device__ __forceinline__ void bucket_sort_body(int b,
                                                 const unsigned* __restrict__ tmp,
                                                 const int* __restrict__ bstart,
                                                 unsigned* __restrict__ csr2,
                                                 int* __restrict__ rp,
                                                 int* __restrict__ deg) {
  __shared__ int cnt[256];
  __shared__ int cur[256];
  __shared__ int wtot2[4];
  const int t = threadIdx.x, lane = t & 63, wid = t >> 6;
  const int p0 = bstart[b], p1 = bstart[b + 1];
  cnt[t] = 0;
  __syncthreads();
  for (int j = p0 + t; j < p1; j += 256) {
    unsigned pr = tmp[j];
    atomicAdd(&cnt[(pr >> 16) & 255u], 1);
  }
  __syncthreads();
  int v = cnt[t];
  int sc = v;
#pragma unroll
  for (int m = 1; m < 64; m <<= 1) {
    int o = __shfl_up(sc, m, 64);
    if (lane >= m) sc += o;
  }
  if (lane == 63) wtot2[wid] = sc;
  __syncthreads();
  int off = 0;
  for (int w = 0; w < wid; ++w) off += wtot2[w];
  const int excl = off + sc - v;
  const int node = b * 256 + t;
  if (node < N_NODES) {
    deg[node] = v;
    rp[node] = p0 + excl;
  }
  cur[t] = excl;
  __syncthreads();
  for (int j = p0 + t; j < p1; j += 256) {
    unsigned pr = tmp[j];
    int ld = (int)((pr >> 16) & 255u);
    int r = atomicAdd(&cur[ld], 1);
    csr2[p0 + r] = pr;  // keep full (s | d<<16)
  }
}

// ---------- MFMA GEMM body (layer 1): h_bf + score columns ----------
__device__ __forceinline__ void gemm_att_body4(int blk,
                                               const ushort* __restrict__ in_bf,
                                               const ushort* __restrict__ wtx,
                                               ushort* __restrict__ h_bf,
                                               float* __restrict__ a_src,
                                               float* __restrict__ a_dst) {
  const int wid = threadIdx.x >> 6;
  const int lane = threadIdx.x & 63;
  const int tile = blk * 4 + wid;
  if (tile >= N_NODES / 16) return;
  const int row0 = tile * 16;
  const int rA = lane & 15;
  const int g = lane >> 4;

  f32x4 acc[9];
#pragma unroll
  for (int ct = 0; ct < 9; ++ct) acc[ct] = (f32x4){0.f, 0.f, 0.f, 0.f};

#pragma unroll
  for (int ks = 0; ks < 4; ++ks) {
    const int k0 = ks * 32 + g * 8;
    bf16x8 af = *(const bf16x8*)(in_bf + (size_t)(row0 + rA) * DIM + k0);
#pragma unroll
    for (int ct = 0; ct < 9; ++ct) {
      bf16x8 bf = *(const bf16x8*)(wtx + (size_t)(ct * 16 + rA) * 128 + k0);
      acc[ct] = __builtin_amdgcn_mfma_f32_16x16x32_bf16(af, bf, acc[ct], 0, 0, 0);
    }
  }

#pragma unroll
  for (int ct = 0; ct < 8; ++ct) {
#pragma unroll
    for (int r = 0; r < 4; ++r) {
      const int row = row0 + g * 4 + r;
      h_bf[(size_t)row * DIM + ct * 16 + rA] = f2bf(acc[ct][r]);
    }
  }
  if (rA < 8) {
#pragma unroll
    for (int r = 0; r < 4; ++r) {
      const int row = row0 + g * 4 + r;
      if (rA < 4)
        a_src[(size_t)row * 4 + rA] = acc[8][r];
      else
        a_dst[(size_t)row * 4 + (rA - 4)] = acc[8][r];
    }
  }
}

// ---------- fused: gemm layer1 (blocks 0..GB-1) || bucket_sort (blocks GB..) ----
__global__ __launch_bounds__(256) void gemm4_sort(
    const ushort* __restrict__ x_bf, const ushort* __restrict__ wtx1,
    ushort* __restrict__ h_bf, float* __restrict__ a_src,
    float* __restrict__ a_dst, const unsigned* __restrict__ tmp,
    const int* __restrict__ bstart, unsigned* __restrict__ csr2,
    int* __restrict__ rp, int* __restrict__ deg) {
  if (blockIdx.x < GB)
    gemm_att_body4(blockIdx.x, x_bf, wtx1, h_bf, a_src, a_dst);
  else
    bucket_sort_body(blockIdx.x - GB, tmp, bstart, csr2, rp, deg);
}

// ---------- layer-1 agg: gather h_bf (per-head alpha) -> z_bf + layer-2 scores --
// R12-proven structure: wave-per-node, phase A/B, per-lane sden, p_lds[wid][4][68].
__global__ __launch_bounds__(256) void node_agg_l1(
    const int* __restrict__ rp, const int* __restrict__ deg,
    const unsigned* __restrict__ csr2, const ushort* __restrict__ h_bf,
    const float* __restrict__ a_srcv, const float* __restrict__ a_dstv,
    const float* __restrict__ bias, const float* __restrict__ w_as2,
    const float* __restrict__ w_ad2, ushort* __restrict__ z_bf,
    float* __restrict__ a_src2, float* __restrict__ a_dst2) {
  __shared__ float p_lds[4][4][68];
  __shared__ int s_lds[4][64];
  const int wid = threadIdx.x >> 6;
  const int lane = threadIdx.x & 63;
  const int node = blockIdx.x * 4 + wid;
  const int head = lane >> 4;  // lane owns features 2*lane, 2*lane+1
  const int beg = rp[node];
  const int dg = deg[node];

  float ad[4];
#pragma unroll
  for (int h = 0; h < 4; ++h) ad[h] = a_dstv[(size_t)node * 4 + h];

  float sden = 0.f, ax = 0.f, ay = 0.f;

  for (int c0 = 0; c0 < dg; c0 += 64) {
    const int cnt = min(64, dg - c0);
    if (lane < cnt) {
      int s = (int)(csr2[beg + c0 + lane] & 0xFFFFu);
      s_lds[wid][lane] = s;
      float4 as4 = ((const float4*)a_srcv)[s];
      float vv[4] = {as4.x, as4.y, as4.z, as4.w};
#pragma unroll
      for (int h = 0; h < 4; ++h) {
        float v = vv[h] + ad[h];
        v = v > 0.f ? v : NEG_SLOPE * v;
        v = fminf(fmaxf(v, -60.f), 80.f);
        p_lds[wid][h][lane] = __expf(v);
      }
    }
    int j = 0;
    for (; j + 8 <= cnt; j += 8) {
#pragma unroll
      for (int u = 0; u < 8; ++u) {
        int s = s_lds[wid][j + u];
        float p = p_lds[wid][head][j + u];
        uint hv = *(const uint*)(h_bf + (size_t)s * DIM + 2 * lane);
        ax += p * bf2f_lo(hv);
        ay += p * bf2f_hi(hv);
        sden += p;
      }
    }
    for (; j < cnt; ++j) {
      int s = s_lds[wid][j];
      float p = p_lds[wid][head][j];
      uint hv = *(const uint*)(h_bf + (size_t)s * DIM + 2 * lane);
      ax += p * bf2f_lo(hv);
      ay += p * bf2f_hi(hv);
      sden += p;
    }
  }

  const float inv = 1.f / sden;
  float2 bv = ((const float2*)bias)[lane];
  float ox = fmaxf(ax * inv + bv.x, 0.f);
  float oy = fmaxf(ay * inv + bv.y, 0.f);
  uint u = (uint)f2bf(ox) | ((uint)f2bf(oy) << 16);
  ((uint*)(z_bf + (size_t)node * DIM))[lane] = u;

  // layer-2 scores from exact f32 z: a2[n] = z . (W2 @ att2)
  float2 ws = ((const float2*)w_as2)[lane];
  float2 wd = ((const float2*)w_ad2)[lane];
  float ps = ox * ws.x + oy * ws.y;
  float pd = ox * wd.x + oy * wd.y;
#pragma unroll
  for (int m = 1; m < 64; m <<= 1) {
    ps += __shfl_xor(ps, m);
    pd += __shfl_xor(pd, m);
  }
  if (lane == 0) {
    a_src2[node] = ps;
    a_dst2[node] = pd;
  }
}

// ---------- layer-2 agg: gather z_bf (H=1, linearity exact) + W2 MFMA epilogue --
// u2 = sum(alpha*z); out = relu(u2 @ W2 + b2). 4 waves = 4 nodes = A rows 0-3.
__global__ __launch_bounds__(256) void node_agg_l2(
    const int* __restrict__ rp, const int* __restrict__ deg,
    const unsigned* __restrict__ csr2, const ushort* __restrict__ z_bf,
    const float* __restrict__ a_src2, const float* __restrict__ a_dst2,
    const ushort* __restrict__ wtx2, const float* __restrict__ bias,
    float* __restrict__ outp) {
  __shared__ float p_lds[4][68];
  __shared__ int s_lds[4][64];
  __shared__ ushort u_lds[16][136];  // rows 0-3 valid; stride 272B (bank-safe)
  const int wid = threadIdx.x >> 6;
  const int lane = threadIdx.x & 63;
  const int node = blockIdx.x * 4 + wid;  // exact: 12500*4 == N_NODES
  const int beg = rp[node];
  const int dg = deg[node];
  const float ad = a_dst2[node];

  float sden = 0.f, ax = 0.f, ay = 0.f;

  for (int c0 = 0; c0 < dg; c0 += 64) {
    const int cnt = min(64, dg - c0);
    if (lane < cnt) {
      int s = (int)(csr2[beg + c0 + lane] & 0xFFFFu);
      s_lds[wid][lane] = s;
      float v = a_src2[s] + ad;
      v = v > 0.f ? v : NEG_SLOPE * v;
      v = fminf(fmaxf(v, -60.f), 80.f);
      p_lds[wid][lane] = __expf(v);
    }
    int j = 0;
    for (; j + 8 <= cnt; j += 8) {
#pragma unroll
      for (int u = 0; u < 8; ++u) {
        int s = s_lds[wid][j + u];
        float p = p_lds[wid][j + u];
        uint hv = *(const uint*)(z_bf + (size_t)s * DIM + 2 * lane);
        ax += p * bf2f_lo(hv);
        ay += p * bf2f_hi(hv);
        sden += p;
      }
    }
    for (; j < cnt; ++j) {
      int s = s_lds[wid][j];
      float p = p_lds[wid][j];
      uint hv = *(const uint*)(z_bf + (size_t)s * DIM + 2 * lane);
      ax += p * bf2f_lo(hv);
      ay += p * bf2f_hi(hv);
      sden += p;
    }
  }

  // u2 row (bf16) -> LDS row wid (no bias yet; bias after GEMM)
  const float inv = 1.f / sden;
  uint upk = (uint)f2bf(ax * inv) | ((uint)f2bf(ay * inv) << 16);
  ((uint*)(&u_lds[wid][0]))[lane] = upk;
  __syncthreads();

  // epilogue: out rows 0-3 = u2 @ W2; wave wid covers cols [wid*32, wid*32+32)
  const int rA = lane & 15;
  const int g = lane >> 4;
  f32x4 acc0 = {0.f, 0.f, 0.f, 0.f}, acc1 = acc0;
#pragma unroll
  for (int ks = 0; ks < 4; ++ks) {
    const int k0 = ks * 32 + g * 8;
    bf16x8 af = *(const bf16x8*)&u_lds[rA][k0];
    bf16x8 b0 = *(const bf16x8*)(wtx2 + (size_t)(wid * 32 + rA) * 128 + k0);
    bf16x8 b1 = *(const bf16x8*)(wtx2 + (size_t)(wid * 32 + 16 + rA) * 128 + k0);
    acc0 = __builtin_amdgcn_mfma_f32_16x16x32_bf16(af, b0, acc0, 0, 0, 0);
    acc1 = __builtin_amdgcn_mfma_f32_16x16x32_bf16(af, b1, acc1, 0, 0, 0);
  }
  if (g == 0) {  // D rows 0-3 (this block's 4 nodes) live in regs of lanes 0-15
#pragma unroll
    for (int q = 0; q < 2; ++q) {
      const int col = wid * 32 + q * 16 + rA;
      const float bv = bias[col];
      const f32x4 a = q == 0 ? acc0 : acc1;
#pragma unroll
      for (int r = 0; r < 4; ++r) {
        outp[(size_t)(blockIdx.x * 4 + r) * DIM + col] = fmaxf(a[r] + bv, 0.f);
      }
    }
  }
}

extern "C" void kernel_launch(void* const* d_in, const int* in_sizes, int n_in,
                              void* d_out, int out_size, void* d_ws, size_t ws_size,
                              hipStream_t stream) {
  const float* x   = (const float*)d_in[0];
  const int*   ei  = (const int*)d_in[1];
  const float* W1  = (const float*)d_in[2];
  const float* as1 = (const float*)d_in[3];
  const float* ad1 = (const float*)d_in[4];
  const float* b1  = (const float*)d_in[5];
  const float* W2  = (const float*)d_in[6];
  const float* as2 = (const float*)d_in[7];
  const float* ad2 = (const float*)d_in[8];
  const float* b2  = (const float*)d_in[9];
  float* out = (float*)d_out;

  char* ws = (char*)d_ws;
  const size_t F_H = (size_t)N_NODES * DIM;  // 6.4M elems
  ushort*   h_bf    = (ushort*)ws;                    // 12.8 MB
  ushort*   z_bf    = h_bf + F_H;                     // 12.8 MB
  ushort*   x_bf    = z_bf + F_H;                     // 12.8 MB
  float*    a_src1  = (float*)(x_bf + F_H);           // 200,000 f32
  float*    a_dst1  = a_src1 + 200000;                // 200,000
  float*    a_src2  = a_dst1 + 200000;                // 50,000
  float*    a_dst2  = a_src2 + N_NODES;               // 50,000
  int*      deg     = (int*)(a_dst2 + N_NODES);       // 50,000
  int*      rp      = deg + N_NODES;                  // 50,000
  unsigned* csr2    = (unsigned*)(rp + N_NODES);      // 850,000
  unsigned* tmp     = csr2 + E_TOT;                   // 850,000
  unsigned* pairs   = tmp + E_TOT;                    // 850,000
  int*      hist_mat= (int*)(pairs + E_TOT);          // 208*196
  int*      bstart  = hist_mat + NBLK_E * NBUCK;      // NBUCK+1
  ushort*   wtx1    = (ushort*)(bstart + NBUCK + 3);  // 144*128 bf16
  ushort*   wtx2    = wtx1 + 144 * 128;               // 128*128 bf16
  float*    w_as2   = (float*)(wtx2 + 128 * 128);     // 128 f32
  float*    w_ad2   = w_as2 + 128;                    // 128

  const int MEGA = 137 + CONV_BLKS + NBLK_E;  // 3470
  const int AGG_B = N_NODES / 4;              // 12500

  hipLaunchKernelGGL(mega_setup, dim3(MEGA), dim3(256), 0, stream,
                     ei, hist_mat, pairs, W1, as1, ad1, W2, as2, ad2,
                     x, x_bf, wtx1, wtx2, w_as2, w_ad2);
  hipLaunchKernelGGL(bucket_scatter, dim3(NBLK_E), dim3(256), 0, stream,
                     pairs, hist_mat, tmp, bstart);
  // bucket_sort (196 blocks) runs concurrently with layer-1 GEMM (782 blocks)
  hipLaunchKernelGGL(gemm4_sort, dim3(GB + NBUCK), dim3(256), 0, stream,
                     x_bf, wtx1, h_bf, a_src1, a_dst1, tmp, bstart, csr2, rp, deg);
  // layer 1: gather h -> z_bf + layer-2 scores
  hipLaunchKernelGGL(node_agg_l1, dim3(AGG_B), dim3(256), 0, stream,
                     rp, deg, csr2, h_bf, a_src1, a_dst1, b1, w_as2, w_ad2,
                     z_bf, a_src2, a_dst2);
  // layer 2: gather z -> MFMA W2 epilogue -> out
  hipLaunchKernelGGL(node_agg_l2, dim3(AGG_B), dim3(256), 0, stream,
                     rp, deg, csr2, z_bf, a_src2, a_dst2, wtx2, b2, out);
}

// Round 15
// 159.897 us; speedup vs baseline: 1.1063x; 1.1063x over previous
//
#include <hip/hip_runtime.h>
#include <hip/hip_bf16.h>
#include <cstddef>

#define N_NODES 50000
#define N_EDGES_RAW 800000
#define E_TOT (N_EDGES_RAW + N_NODES) /* 850000 */
#define DIM 128
#define NEG_SLOPE 0.2f

#define NBUCK 196            /* ceil(50000/256) buckets of 256 nodes */
#define CHUNK 4096           /* edges per block in bucket passes */
#define NBLK_E ((E_TOT + CHUNK - 1) / CHUNK) /* 208 */
#define CONV_BLKS 3125       /* 6.4M f32 -> bf16, 2048 elems/block */
#define GB 782               /* gemm blocks: ceil(3125 tiles / 4 waves) */

typedef __attribute__((ext_vector_type(8))) short bf16x8;
typedef __attribute__((ext_vector_type(4))) float f32x4;

// round-to-nearest-even f32 -> bf16 bits
__device__ __forceinline__ ushort f2bf(float f) {
  unsigned u = __float_as_uint(f);
  return (ushort)((u + 0x7FFFu + ((u >> 16) & 1u)) >> 16);
}
__device__ __forceinline__ float bf2f_lo(uint u) {
  return __uint_as_float(u << 16);
}
__device__ __forceinline__ float bf2f_hi(uint u) {
  return __uint_as_float(u & 0xFFFF0000u);
}

// ---------- edge fetch robust to int32 vs int64 storage of edge_index ----------
__device__ __forceinline__ void get_edge(const int* __restrict__ ei, int is64,
                                         int e, int& s, int& d) {
  if (e >= N_EDGES_RAW) { s = e - N_EDGES_RAW; d = s; return; }
  if (is64) {
    s = ei[2 * (size_t)e];
    d = ei[2 * ((size_t)N_EDGES_RAW + (size_t)e)];
  } else {
    s = ei[e];
    d = ei[N_EDGES_RAW + e];
  }
}

__device__ __forceinline__ int detect_inline(const int* __restrict__ ei,
                                             int* sflag) {
  const int t = threadIdx.x;
  if (t < 64) {
    int hi = ei[2 * t + 1];
    unsigned long long b = __ballot(hi != 0);
    if (t == 0) *sflag = (b == 0ULL) ? 1 : 0;
  }
  __syncthreads();
  return *sflag;
}

// ---------- WtX1[144][128] bf16 prep (W1^T + score columns) ----------
__device__ __forceinline__ void prep_one(const float* __restrict__ w,
                                         const float* __restrict__ atts,
                                         const float* __restrict__ attd,
                                         ushort* __restrict__ wtx,
                                         int H, int idx) {
  const int c = idx >> 7, k = idx & 127;
  const int C = 128 / H;
  float v;
  if (c < 128) {
    v = w[k * 128 + c];
  } else if (c < 128 + H) {
    const int hd = c - 128;
    float s = 0.f;
    for (int j = 0; j < C; ++j) s += w[k * 128 + hd * C + j] * atts[hd * C + j];
    v = s;
  } else if (c < 128 + 2 * H) {
    const int hd = c - 128 - H;
    float s = 0.f;
    for (int j = 0; j < C; ++j) s += w[k * 128 + hd * C + j] * attd[hd * C + j];
    v = s;
  } else {
    v = 0.f;
  }
  wtx[idx] = f2bf(v);
}

// ---------- mega: wtx1 | wtx2 (W2^T) | w_as2/w_ad2 | x->bf16 | hist+pairs ----
__global__ __launch_bounds__(256) void mega_setup(
    const int* __restrict__ ei, int* __restrict__ hist_mat,
    unsigned* __restrict__ pairs,
    const float* __restrict__ W1, const float* __restrict__ as1,
    const float* __restrict__ ad1,
    const float* __restrict__ W2, const float* __restrict__ as2,
    const float* __restrict__ ad2,
    const float* __restrict__ x, ushort* __restrict__ x_bf,
    ushort* __restrict__ wtx1, ushort* __restrict__ wtx2,
    float* __restrict__ w_as2, float* __restrict__ w_ad2) {
  const int b = blockIdx.x, t = threadIdx.x;
  if (b < 72) {
    prep_one(W1, as1, ad1, wtx1, 4, b * 256 + t);
  } else if (b < 136) {
    const int idx = (b - 72) * 256 + t;  // 0..16383
    const int c = idx >> 7, k = idx & 127;
    wtx2[idx] = f2bf(W2[k * 128 + c]);   // wtx2[c][k] = W2[k][c]
  } else if (b == 136) {
    if (t < 128) {
      float s2 = 0.f, d2 = 0.f;
      for (int c = 0; c < 128; ++c) {
        float w = W2[t * 128 + c];
        s2 += w * as2[c];
        d2 += w * ad2[c];
      }
      w_as2[t] = s2;
      w_ad2[t] = d2;
    }
  } else if (b < 137 + CONV_BLKS) {
    const int base = (b - 137) * 2048 + t * 8;
    float4 v0 = *(const float4*)(x + base);
    float4 v1 = *(const float4*)(x + base + 4);
    ushort u[8];
    u[0] = f2bf(v0.x); u[1] = f2bf(v0.y); u[2] = f2bf(v0.z); u[3] = f2bf(v0.w);
    u[4] = f2bf(v1.x); u[5] = f2bf(v1.y); u[6] = f2bf(v1.z); u[7] = f2bf(v1.w);
    *(uint4*)(x_bf + base) = *(const uint4*)u;
  } else {
    __shared__ int hist[NBUCK];
    __shared__ int sflag;
    const int cb = b - 137 - CONV_BLKS;
    if (t < NBUCK) hist[t] = 0;
    const int is64 = detect_inline(ei, &sflag);  // has __syncthreads
    __syncthreads();
    const int e0 = cb * CHUNK;
#pragma unroll
    for (int i = 0; i < CHUNK / 256; ++i) {
      int e = e0 + i * 256 + t;
      if (e < E_TOT) {
        int s, d;
        get_edge(ei, is64, e, s, d);
        pairs[e] = (unsigned)s | ((unsigned)d << 16);
        atomicAdd(&hist[d >> 8], 1);
      }
    }
    __syncthreads();
    if (t < NBUCK) hist_mat[cb * NBUCK + t] = hist[t];
  }
}

// ---------- scatter with self-computed deterministic bases (no global atomics) --
__global__ __launch_bounds__(256) void bucket_scatter(
    const unsigned* __restrict__ pairs, const int* __restrict__ hist_mat,
    unsigned* __restrict__ tmp, int* __restrict__ bstart_g) {
  __shared__ int wtot[4];
  __shared__ int sbase[NBUCK];
  __shared__ int shist[NBUCK];
  const int b = blockIdx.x, t = threadIdx.x, lane = t & 63, wid = t >> 6;
  int tot = 0, pre = 0;
  if (t < NBUCK) {
    for (int bb = 0; bb < NBLK_E; ++bb) {
      int v = hist_mat[bb * NBUCK + t];
      pre += (bb < b) ? v : 0;
      tot += v;
    }
    shist[t] = 0;
  }
  int sc = tot;
#pragma unroll
  for (int m = 1; m < 64; m <<= 1) {
    int o = __shfl_up(sc, m, 64);
    if (lane >= m) sc += o;
  }
  if (lane == 63) wtot[wid] = sc;
  __syncthreads();
  int off = 0;
  for (int w = 0; w < wid; ++w) off += wtot[w];
  const int excl = off + sc - tot;
  if (t < NBUCK) sbase[t] = excl + pre;
  if (b == 0) {
    if (t < NBUCK) bstart_g[t] = excl;
    if (t == 255) bstart_g[NBUCK] = off + sc;
  }
  __syncthreads();
  const int e0 = b * CHUNK;
  unsigned pr_[CHUNK / 256];
  int rk[CHUNK / 256];
#pragma unroll
  for (int i = 0; i < CHUNK / 256; ++i) {
    int e = e0 + i * 256 + t;
    if (e < E_TOT) {
      unsigned pr = pairs[e];
      pr_[i] = pr;
      rk[i] = atomicAdd(&shist[pr >> 24], 1);
    }
  }
#pragma unroll
  for (int i = 0; i < CHUNK / 256; ++i) {
    int e = e0 + i * 256 + t;
    if (e < E_TOT) tmp[sbase[pr_[i] >> 24] + rk[i]] = pr_[i];
  }
}

// ---------- per-bucket counting sort body (emits PACKED (s|d<<16) csr) --------
__device__ __forceinline__ void bucket_sort_body(int b,
                                                 const unsigned* __restrict__ tmp,
                                                 const int* __restrict__ bstart,
                                                 unsigned* __restrict__ csr2,
                                                 int* __restrict__ rp,
                                                 int* __restrict__ deg) {
  __shared__ int cnt[256];
  __shared__ int cur[256];
  __shared__ int wtot2[4];
  const int t = threadIdx.x, lane = t & 63, wid = t >> 6;
  const int p0 = bstart[b], p1 = bstart[b + 1];
  cnt[t] = 0;
  __syncthreads();
  for (int j = p0 + t; j < p1; j += 256) {
    unsigned pr = tmp[j];
    atomicAdd(&cnt[(pr >> 16) & 255u], 1);
  }
  __syncthreads();
  int v = cnt[t];
  int sc = v;
#pragma unroll
  for (int m = 1; m < 64; m <<= 1) {
    int o = __shfl_up(sc, m, 64);
    if (lane >= m) sc += o;
  }
  if (lane == 63) wtot2[wid] = sc;
  __syncthreads();
  int off = 0;
  for (int w = 0; w < wid; ++w) off += wtot2[w];
  const int excl = off + sc - v;
  const int node = b * 256 + t;
  if (node < N_NODES) {
    deg[node] = v;
    rp[node] = p0 + excl;
  }
  cur[t] = excl;
  __syncthreads();
  for (int j = p0 + t; j < p1; j += 256) {
    unsigned pr = tmp[j];
    int ld = (int)((pr >> 16) & 255u);
    int r = atomicAdd(&cur[ld], 1);
    csr2[p0 + r] = pr;  // keep full (s | d<<16)
  }
}

// ---------- MFMA GEMM body (layer 1): h_bf + score columns ----------
__device__ __forceinline__ void gemm_att_body4(int blk,
                                               const ushort* __restrict__ in_bf,
                                               const ushort* __restrict__ wtx,
                                               ushort* __restrict__ h_bf,
                                               float* __restrict__ a_src,
                                               float* __restrict__ a_dst) {
  const int wid = threadIdx.x >> 6;
  const int lane = threadIdx.x & 63;
  const int tile = blk * 4 + wid;
  if (tile >= N_NODES / 16) return;
  const int row0 = tile * 16;
  const int rA = lane & 15;
  const int g = lane >> 4;

  f32x4 acc[9];
#pragma unroll
  for (int ct = 0; ct < 9; ++ct) acc[ct] = (f32x4){0.f, 0.f, 0.f, 0.f};

#pragma unroll
  for (int ks = 0; ks < 4; ++ks) {
    const int k0 = ks * 32 + g * 8;
    bf16x8 af = *(const bf16x8*)(in_bf + (size_t)(row0 + rA) * DIM + k0);
#pragma unroll
    for (int ct = 0; ct < 9; ++ct) {
      bf16x8 bf = *(const bf16x8*)(wtx + (size_t)(ct * 16 + rA) * 128 + k0);
      acc[ct] = __builtin_amdgcn_mfma_f32_16x16x32_bf16(af, bf, acc[ct], 0, 0, 0);
    }
  }

#pragma unroll
  for (int ct = 0; ct < 8; ++ct) {
#pragma unroll
    for (int r = 0; r < 4; ++r) {
      const int row = row0 + g * 4 + r;
      h_bf[(size_t)row * DIM + ct * 16 + rA] = f2bf(acc[ct][r]);
    }
  }
  if (rA < 8) {
#pragma unroll
    for (int r = 0; r < 4; ++r) {
      const int row = row0 + g * 4 + r;
      if (rA < 4)
        a_src[(size_t)row * 4 + rA] = acc[8][r];
      else
        a_dst[(size_t)row * 4 + (rA - 4)] = acc[8][r];
    }
  }
}

// ---------- fused: gemm layer1 (blocks 0..GB-1) || bucket_sort (blocks GB..) ----
__global__ __launch_bounds__(256) void gemm4_sort(
    const ushort* __restrict__ x_bf, const ushort* __restrict__ wtx1,
    ushort* __restrict__ h_bf, float* __restrict__ a_src,
    float* __restrict__ a_dst, const unsigned* __restrict__ tmp,
    const int* __restrict__ bstart, unsigned* __restrict__ csr2,
    int* __restrict__ rp, int* __restrict__ deg) {
  if (blockIdx.x < GB)
    gemm_att_body4(blockIdx.x, x_bf, wtx1, h_bf, a_src, a_dst);
  else
    bucket_sort_body(blockIdx.x - GB, tmp, bstart, csr2, rp, deg);
}

// ---------- plain MFMA GEMM (layer 2): h2 = z @ W2, 8 col-tiles, no scores ----
__global__ __launch_bounds__(256) void gemm_plain(const ushort* __restrict__ in_bf,
                                                  const ushort* __restrict__ wtx,
                                                  ushort* __restrict__ h_out) {
  const int wid = threadIdx.x >> 6;
  const int lane = threadIdx.x & 63;
  const int tile = blockIdx.x * 4 + wid;
  if (tile >= N_NODES / 16) return;
  const int row0 = tile * 16;
  const int rA = lane & 15;
  const int g = lane >> 4;

  f32x4 acc[8];
#pragma unroll
  for (int ct = 0; ct < 8; ++ct) acc[ct] = (f32x4){0.f, 0.f, 0.f, 0.f};

#pragma unroll
  for (int ks = 0; ks < 4; ++ks) {
    const int k0 = ks * 32 + g * 8;
    bf16x8 af = *(const bf16x8*)(in_bf + (size_t)(row0 + rA) * DIM + k0);
#pragma unroll
    for (int ct = 0; ct < 8; ++ct) {
      bf16x8 bf = *(const bf16x8*)(wtx + (size_t)(ct * 16 + rA) * 128 + k0);
      acc[ct] = __builtin_amdgcn_mfma_f32_16x16x32_bf16(af, bf, acc[ct], 0, 0, 0);
    }
  }

#pragma unroll
  for (int ct = 0; ct < 8; ++ct) {
#pragma unroll
    for (int r = 0; r < 4; ++r) {
      const int row = row0 + g * 4 + r;
      h_out[(size_t)row * DIM + ct * 16 + rA] = f2bf(acc[ct][r]);
    }
  }
}

// ---------- layer-1 agg: gather h_bf (per-head alpha) -> z_bf + layer-2 scores --
// R12-proven structure: wave-per-node, phase A/B, per-lane sden, p_lds[wid][4][68].
__global__ __launch_bounds__(256) void node_agg_l1(
    const int* __restrict__ rp, const int* __restrict__ deg,
    const unsigned* __restrict__ csr2, const ushort* __restrict__ h_bf,
    const float* __restrict__ a_srcv, const float* __restrict__ a_dstv,
    const float* __restrict__ bias, const float* __restrict__ w_as2,
    const float* __restrict__ w_ad2, ushort* __restrict__ z_bf,
    float* __restrict__ a_src2, float* __restrict__ a_dst2) {
  __shared__ float p_lds[4][4][68];
  __shared__ int s_lds[4][64];
  const int wid = threadIdx.x >> 6;
  const int lane = threadIdx.x & 63;
  const int node = blockIdx.x * 4 + wid;
  const int head = lane >> 4;  // lane owns features 2*lane, 2*lane+1
  const int beg = rp[node];
  const int dg = deg[node];

  float ad[4];
#pragma unroll
  for (int h = 0; h < 4; ++h) ad[h] = a_dstv[(size_t)node * 4 + h];

  float sden = 0.f, ax = 0.f, ay = 0.f;

  for (int c0 = 0; c0 < dg; c0 += 64) {
    const int cnt = min(64, dg - c0);
    if (lane < cnt) {
      int s = (int)(csr2[beg + c0 + lane] & 0xFFFFu);
      s_lds[wid][lane] = s;
      float4 as4 = ((const float4*)a_srcv)[s];
      float vv[4] = {as4.x, as4.y, as4.z, as4.w};
#pragma unroll
      for (int h = 0; h < 4; ++h) {
        float v = vv[h] + ad[h];
        v = v > 0.f ? v : NEG_SLOPE * v;
        v = fminf(fmaxf(v, -60.f), 80.f);
        p_lds[wid][h][lane] = __expf(v);
      }
    }
    int j = 0;
    for (; j + 8 <= cnt; j += 8) {
#pragma unroll
      for (int u = 0; u < 8; ++u) {
        int s = s_lds[wid][j + u];
        float p = p_lds[wid][head][j + u];
        uint hv = *(const uint*)(h_bf + (size_t)s * DIM + 2 * lane);
        ax += p * bf2f_lo(hv);
        ay += p * bf2f_hi(hv);
        sden += p;
      }
    }
    for (; j < cnt; ++j) {
      int s = s_lds[wid][j];
      float p = p_lds[wid][head][j];
      uint hv = *(const uint*)(h_bf + (size_t)s * DIM + 2 * lane);
      ax += p * bf2f_lo(hv);
      ay += p * bf2f_hi(hv);
      sden += p;
    }
  }

  const float inv = 1.f / sden;
  float2 bv = ((const float2*)bias)[lane];
  float ox = fmaxf(ax * inv + bv.x, 0.f);
  float oy = fmaxf(ay * inv + bv.y, 0.f);
  uint u = (uint)f2bf(ox) | ((uint)f2bf(oy) << 16);
  ((uint*)(z_bf + (size_t)node * DIM))[lane] = u;

  // layer-2 scores from exact f32 z: a2[n] = z . (W2 @ att2)
  float2 ws = ((const float2*)w_as2)[lane];
  float2 wd = ((const float2*)w_ad2)[lane];
  float ps = ox * ws.x + oy * ws.y;
  float pd = ox * wd.x + oy * wd.y;
#pragma unroll
  for (int m = 1; m < 64; m <<= 1) {
    ps += __shfl_xor(ps, m);
    pd += __shfl_xor(pd, m);
  }
  if (lane == 0) {
    a_src2[node] = ps;
    a_dst2[node] = pd;
  }
}

// ---------- layer-2 agg: gather h2 (R12-proven, barrier-free) -> f32 out ------
__global__ __launch_bounds__(256) void node_agg_l2(
    const int* __restrict__ rp, const int* __restrict__ deg,
    const unsigned* __restrict__ csr2, const ushort* __restrict__ h2,
    const float* __restrict__ a_src2, const float* __restrict__ a_dst2,
    const float* __restrict__ bias, float* __restrict__ outp) {
  __shared__ float p_lds[4][68];
  __shared__ int s_lds[4][64];
  const int wid = threadIdx.x >> 6;
  const int lane = threadIdx.x & 63;
  const int node = blockIdx.x * 4 + wid;  // exact: 12500*4 == N_NODES
  const int beg = rp[node];
  const int dg = deg[node];
  const float ad = a_dst2[node];

  float sden = 0.f, ax = 0.f, ay = 0.f;

  for (int c0 = 0; c0 < dg; c0 += 64) {
    const int cnt = min(64, dg - c0);
    if (lane < cnt) {
      int s = (int)(csr2[beg + c0 + lane] & 0xFFFFu);
      s_lds[wid][lane] = s;
      float v = a_src2[s] + ad;
      v = v > 0.f ? v : NEG_SLOPE * v;
      v = fminf(fmaxf(v, -60.f), 80.f);
      p_lds[wid][lane] = __expf(v);
    }
    int j = 0;
    for (; j + 8 <= cnt; j += 8) {
#pragma unroll
      for (int u = 0; u < 8; ++u) {
        int s = s_lds[wid][j + u];
        float p = p_lds[wid][j + u];
        uint hv = *(const uint*)(h2 + (size_t)s * DIM + 2 * lane);
        ax += p * bf2f_lo(hv);
        ay += p * bf2f_hi(hv);
        sden += p;
      }
    }
    for (; j < cnt; ++j) {
      int s = s_lds[wid][j];
      float p = p_lds[wid][j];
      uint hv = *(const uint*)(h2 + (size_t)s * DIM + 2 * lane);
      ax += p * bf2f_lo(hv);
      ay += p * bf2f_hi(hv);
      sden += p;
    }
  }

  const float inv = 1.f / sden;
  float2 bv = ((const float2*)bias)[lane];
  float ox = fmaxf(ax * inv + bv.x, 0.f);
  float oy = fmaxf(ay * inv + bv.y, 0.f);
  ((float2*)(outp + (size_t)node * DIM))[lane] = make_float2(ox, oy);
}

extern "C" void kernel_launch(void* const* d_in, const int* in_sizes, int n_in,
                              void* d_out, int out_size, void* d_ws, size_t ws_size,
                              hipStream_t stream) {
  const float* x   = (const float*)d_in[0];
  const int*   ei  = (const int*)d_in[1];
  const float* W1  = (const float*)d_in[2];
  const float* as1 = (const float*)d_in[3];
  const float* ad1 = (const float*)d_in[4];
  const float* b1  = (const float*)d_in[5];
  const float* W2  = (const float*)d_in[6];
  const float* as2 = (const float*)d_in[7];
  const float* ad2 = (const float*)d_in[8];
  const float* b2  = (const float*)d_in[9];
  float* out = (float*)d_out;

  char* ws = (char*)d_ws;
  const size_t F_H = (size_t)N_NODES * DIM;  // 6.4M elems
  ushort*   h_bf    = (ushort*)ws;                    // 12.8 MB (layer-1 h)
  ushort*   z_bf    = h_bf + F_H;                     // 12.8 MB
  ushort*   x_bf    = z_bf + F_H;                     // 12.8 MB (reused as h2)
  float*    a_src1  = (float*)(x_bf + F_H);           // 200,000 f32
  float*    a_dst1  = a_src1 + 200000;                // 200,000
  float*    a_src2  = a_dst1 + 200000;                // 50,000
  float*    a_dst2  = a_src2 + N_NODES;               // 50,000
  int*      deg     = (int*)(a_dst2 + N_NODES);       // 50,000
  int*      rp      = deg + N_NODES;                  // 50,000
  unsigned* csr2    = (unsigned*)(rp + N_NODES);      // 850,000
  unsigned* tmp     = csr2 + E_TOT;                   // 850,000
  unsigned* pairs   = tmp + E_TOT;                    // 850,000
  int*      hist_mat= (int*)(pairs + E_TOT);          // 208*196
  int*      bstart  = hist_mat + NBLK_E * NBUCK;      // NBUCK+1
  ushort*   wtx1    = (ushort*)(bstart + NBUCK + 3);  // 144*128 bf16
  ushort*   wtx2    = wtx1 + 144 * 128;               // 128*128 bf16
  float*    w_as2   = (float*)(wtx2 + 128 * 128);     // 128 f32
  float*    w_ad2   = w_as2 + 128;                    // 128

  const int MEGA = 137 + CONV_BLKS + NBLK_E;  // 3470
  const int AGG_B = N_NODES / 4;              // 12500
  ushort* h2 = x_bf;  // x_bf is dead after gemm4_sort; reuse for h2

  hipLaunchKernelGGL(mega_setup, dim3(MEGA), dim3(256), 0, stream,
                     ei, hist_mat, pairs, W1, as1, ad1, W2, as2, ad2,
                     x, x_bf, wtx1, wtx2, w_as2, w_ad2);
  hipLaunchKernelGGL(bucket_scatter, dim3(NBLK_E), dim3(256), 0, stream,
                     pairs, hist_mat, tmp, bstart);
  // bucket_sort (196 blocks) runs concurrently with layer-1 GEMM (782 blocks)
  hipLaunchKernelGGL(gemm4_sort, dim3(GB + NBUCK), dim3(256), 0, stream,
                     x_bf, wtx1, h_bf, a_src1, a_dst1, tmp, bstart, csr2, rp, deg);
  // layer 1: gather h -> z_bf + layer-2 scores (barrier-free, proven)
  hipLaunchKernelGGL(node_agg_l1, dim3(AGG_B), dim3(256), 0, stream,
                     rp, deg, csr2, h_bf, a_src1, a_dst1, b1, w_as2, w_ad2,
                     z_bf, a_src2, a_dst2);
  // layer 2: h2 = z @ W2 (plain GEMM), then gather h2 -> out
  hipLaunchKernelGGL(gemm_plain, dim3(GB), dim3(256), 0, stream,
                     z_bf, wtx2, h2);
  hipLaunchKernelGGL(node_agg_l2, dim3(AGG_B), dim3(256), 0, stream,
                     rp, deg, csr2, h2, a_src2, a_dst2, b2, out);
}